// Round 5
// baseline (8751.839 us; speedup 1.0000x reference)
//
#include <hip/hip_runtime.h>
#include <hip/hip_fp16.h>
#include <math.h>

#define BB 64
#define TT 32
#define ENCL 128
#define DD 800
#define TPB 1024

typedef _Float16 h2 __attribute__((ext_vector_type(2)));

__device__ __forceinline__ h2 u2h(unsigned u) { union { unsigned u; h2 h; } c; c.u = u; return c.h; }
__device__ __forceinline__ unsigned pack2(float a, float b) {
    union { unsigned u; h2 h; } c; c.h[0] = (_Float16)a; c.h[1] = (_Float16)b; return c.u;
}
__device__ __forceinline__ float sigf(float x) { return 1.f / (1.f + __expf(-x)); }
__device__ __forceinline__ float wred(float v) {
#pragma unroll
    for (int o = 32; o > 0; o >>= 1) v += __shfl_xor(v, o);
    return v;
}
__device__ __forceinline__ float wmax(float v) {
#pragma unroll
    for (int o = 32; o > 0; o >>= 1) v = fmaxf(v, __shfl_xor(v, o));
    return v;
}

#if __has_builtin(__builtin_amdgcn_fdot2)
__device__ __forceinline__ float FDOT2(h2 a, h2 b, float c) { return __builtin_amdgcn_fdot2(a, b, c, false); }
#else
__device__ __forceinline__ float FDOT2(h2 a, h2 b, float c) {
    return c + (float)a[0] * (float)b[0] + (float)a[1] * (float)b[1];
}
#endif

__device__ __forceinline__ float dot8(uint4 w, uint4 x, float acc) {
    acc = FDOT2(u2h(w.x), u2h(x.x), acc);
    acc = FDOT2(u2h(w.y), u2h(x.y), acc);
    acc = FDOT2(u2h(w.z), u2h(x.z), acc);
    acc = FDOT2(u2h(w.w), u2h(x.w), acc);
    return acc;
}

// ---- prep: W[1600][800] f32 -> [200][800] uint4 (8 consecutive k as half) ----
__global__ __launch_bounds__(256) void pack_w8(const float* __restrict__ W, uint4* __restrict__ out) {
    int i = blockIdx.x * 256 + threadIdx.x;          // 160000
    if (i >= 200 * 800) return;
    int c = i % 800, kq = i / 800;
    const float* src = W + (size_t)(8 * kq) * 800 + c;
    uint4 r;
    r.x = pack2(src[0],        src[800]);
    r.y = pack2(src[2 * 800],  src[3 * 800]);
    r.z = pack2(src[4 * 800],  src[5 * 800]);
    r.w = pack2(src[6 * 800],  src[7 * 800]);
    out[i] = r;
}

// ---- prep: f32 pairs -> half2 words ----
__global__ __launch_bounds__(256) void pack_pairs(const float* __restrict__ in, unsigned* __restrict__ out, int n2) {
    int i = blockIdx.x * 256 + threadIdx.x;
    if (i < n2) out[i] = pack2(in[2 * i], in[2 * i + 1]);
}

// ---- prep: head w1 [800][200] f32 -> [400][200] half2 (k-pairs) ----
__global__ __launch_bounds__(256) void pack_w1(const float* __restrict__ w1, unsigned* __restrict__ out) {
    int i = blockIdx.x * 256 + threadIdx.x;          // 80000
    if (i >= 400 * 200) return;
    int c = i % 200, kp = i / 200;
    out[i] = pack2(w1[(2 * kp) * 200 + c], w1[(2 * kp + 1) * 200 + c]);
}

// =================== the whole decoder: one block per batch row ===================
__global__ __launch_bounds__(TPB, 1) void decoder_kernel(
    const float* __restrict__ x, const __half* __restrict__ ench,
    const uint4* __restrict__ iwp0, const uint4* __restrict__ iwp1,
    const uint4* __restrict__ swp0, const uint4* __restrict__ swp1,
    const float* __restrict__ ib0, const float* __restrict__ ib1,
    const float* __restrict__ sb0, const float* __restrict__ sb1,
    const float* __restrict__ cw0, const float* __restrict__ cb0,
    const float* __restrict__ cw1, const float* __restrict__ cb1,
    const float* __restrict__ init_h, const float* __restrict__ init_c,
    __half* __restrict__ PREh, __half* __restrict__ REFh,
    const unsigned* __restrict__ w1p, const float* __restrict__ hb1,
    const float* __restrict__ hw2, const float* __restrict__ hb2,
    const float* __restrict__ hw3, const float* __restrict__ hb3,
    float* __restrict__ out)
{
    __shared__ float cwS[2][1536];
    __shared__ float cbS[2][32];
    __shared__ float HC[2][2][DD];     // [layer][h=0/c=1][d]
    __shared__ float cin[DD];
    __shared__ float hn[DD];
    __shared__ float hv[DD];
    __shared__ alignas(16) unsigned xh[DD];   // GEMV input: 1600 halfs as 800 half2 words
    __shared__ float sc[128];
    __shared__ float pw[128];
    __shared__ float2 pc[400];         // partial-ctx combine buffer

    const int b = blockIdx.x;
    const int tid = threadIdx.x;
    const int lane = tid & 63;
    const int wv = tid >> 6;           // 16 waves
    const int d2 = tid & 511;          // ctx split index
    const int gg = tid >> 9;           // ctx split group (0/1)

    const uint4* iwp[2] = {iwp0, iwp1};
    const uint4* swp[2] = {swp0, swp1};
    const float* ib[2] = {ib0, ib1};
    const float* sb[2] = {sb0, sb1};
    const float* cwA[2] = {cw0, cw1};
    const float* cbA[2] = {cb0, cb1};

    // ---- one-time staging: conv weights (both layers) + initial state ----
    for (int l2 = 0; l2 < 2; ++l2) {
        const int cin_l = l2 ? 16 : 9;
        const int nw = 32 * cin_l * 3;
        for (int i = tid; i < nw; i += TPB) {
            int p = i % 3, rest = i / 3;
            int gt = rest & 3, rest2 = rest >> 2;
            int ic = rest2 % cin_l, ch = rest2 / cin_l;
            cwS[l2][(ch * cin_l + ic) * 12 + gt * 3 + p] = cwA[l2][((gt * 8 + ch) * cin_l + ic) * 3 + p];
        }
        for (int i = tid; i < 32; i += TPB) cbS[l2][i] = cbA[l2][i];
        for (int i = tid; i < DD; i += TPB) {
            HC[l2][0][i] = init_h[((size_t)l2 * BB + b) * DD + i];
            HC[l2][1][i] = init_c[((size_t)l2 * BB + b) * DD + i];
        }
    }
    __syncthreads();

    const unsigned* encu = (const unsigned*)ench;
    const unsigned* encb = encu + (size_t)b * ENCL * 400;
    const uint4* xh4 = (const uint4*)xh;            // 200 uint4 = full GEMV input
    const uint4* xh4h = (const uint4*)(xh + 400);   // h/query half (100 uint4)

    for (int s = 0; s < TT; ++s) {
        for (int l = 0; l < 2; ++l) {
            const int cinx = (l == 0) ? 1 : 8;
            const int cin_l = cinx + 8;
            // ---- A: cell input (l==1: cin already holds layer-0 output) ----
            if (l == 0) {
                for (int i = tid; i < 100; i += TPB) cin[i] = x[((size_t)b * TT + s) * 100 + i];
            }
            __syncthreads();
            // ---- B: ConvLSTM cell ----
            if (tid < DD) {
                const int col = tid % 10, rch = tid / 10;
                const int ch = rch & 7, r = rch >> 3;
                float g0 = cbS[l][ch], g1 = cbS[l][8 + ch], g2 = cbS[l][16 + ch], g3 = cbS[l][24 + ch];
                for (int ic = 0; ic < cin_l; ++ic) {
                    const float* zb = (ic < cinx)
                        ? ((l == 0) ? &cin[r * 10] : &cin[r * 80 + ic * 10])
                        : &HC[l][0][r * 80 + (ic - cinx) * 10];
                    float z0 = (col > 0) ? zb[col - 1] : 0.f;
                    float z1 = zb[col];
                    float z2 = (col < 9) ? zb[col + 1] : 0.f;
                    const float* wr = &cwS[l][(ch * cin_l + ic) * 12];
                    g0 += z0 * wr[0] + z1 * wr[1] + z2 * wr[2];
                    g1 += z0 * wr[3] + z1 * wr[4] + z2 * wr[5];
                    g2 += z0 * wr[6] + z1 * wr[7] + z2 * wr[8];
                    g3 += z0 * wr[9] + z1 * wr[10] + z2 * wr[11];
                }
                float c2 = sigf(g1) * HC[l][1][tid] + sigf(g0) * tanhf(g2);
                float hnv = sigf(g3) * tanhf(c2);
                hn[tid] = hnv;
                HC[l][1][tid] = c2;                     // c: in-place safe (per-thread)
            }
            __syncthreads();
            if (tid < DD) HC[l][0][tid] = hn[tid];      // h: after all neighbor reads
            if (tid < 400) xh[400 + tid] = pack2(hn[2 * tid], hn[2 * tid + 1]);
            __syncthreads();
            // ---- C: inter-attention scores (16 waves x 8 enc rows, uint4 reads) ----
            {
                const uint4* xq0 = xh4h;                // query = h_new
#pragma unroll
                for (int r8 = 0; r8 < 8; ++r8) {
                    const int le = wv * 8 + r8;
                    const uint4* erow4 = (const uint4*)(encb + (size_t)le * 400);
                    float sum = dot8(erow4[lane], xq0[lane], 0.f);
                    if (lane < 36) sum = dot8(erow4[64 + lane], xq0[64 + lane], sum);
                    sum = wred(sum);
                    if (lane == 0) sc[le] = sum;
                }
            }
            __syncthreads();
            // ---- D: softmax over 128 (wave 0) ----
            if (wv == 0) {
                float v0 = sc[lane], v1 = sc[64 + lane];
                float m = wmax(fmaxf(v0, v1));
                float e0 = __expf(v0 - m), e1 = __expf(v1 - m);
                float S = wred(e0 + e1);
                float inv = 1.f / S;
                pw[lane] = e0 * inv;
                pw[64 + lane] = e1 * inv;
            }
            __syncthreads();
            // ---- E: ctx = sum_le pw[le]*enc[b][le][:], split le across 2 groups ----
            if (d2 < 400) {
                float a0 = 0.f, a1 = 0.f;
                const unsigned* ep = encb + (size_t)(gg * 64) * 400 + d2;
#pragma unroll 8
                for (int k = 0; k < 64; ++k) {
                    h2 ev = u2h(ep[(size_t)k * 400]);
                    float w = pw[gg * 64 + k];
                    a0 = fmaf(w, (float)ev[0], a0);
                    a1 = fmaf(w, (float)ev[1], a1);
                }
                if (gg == 1) pc[d2] = make_float2(a0, a1);
                else { hv[2 * d2] = a0; hv[2 * d2 + 1] = a1; }  // stash g=0 partial
            }
            __syncthreads();
            if (tid < 400) xh[tid] = pack2(hv[2 * tid] + pc[tid].x, hv[2 * tid + 1] + pc[tid].y);
            __syncthreads();
            // ---- F: GEMV1: cat(ctx, h) @ iw + ib -> tanh -> hv ----
            if (tid < DD) {
                float acc = ib[l][tid];
                const uint4* wp = iwp[l] + tid;
#pragma unroll 8
                for (int kq = 0; kq < 200; ++kq)
                    acc = dot8(wp[(size_t)kq * 800], xh4[kq], acc);
                float hvv = tanhf(acc);
                hv[tid] = hvv;
                PREh[(((size_t)l * BB + b) * TT + s) * DD + tid] = (__half)hvv;
            }
            __syncthreads();
            if (tid < 400) xh[400 + tid] = pack2(hv[2 * tid], hv[2 * tid + 1]);
            __syncthreads();
            if (s == 0) {
                if (tid < DD) {
                    float v = hv[tid];
                    REFh[(((size_t)l * BB + b) * TT + 0) * DD + tid] = (__half)v;
                    if (l == 0) cin[tid] = v;
                }
                __syncthreads();
            } else {
                // ---- G: self-attn scores over t' < s (query = hv in xh[400..]) ----
                for (int tp = wv; tp < s; tp += 16) {
                    const uint4* pr4 = (const uint4*)((const unsigned*)PREh + (((size_t)l * BB + b) * TT + tp) * 400);
                    float sum = dot8(pr4[lane], xh4h[lane], 0.f);
                    if (lane < 36) sum = dot8(pr4[64 + lane], xh4h[64 + lane], sum);
                    sum = wred(sum);
                    if (lane == 0) sc[tp] = sum;
                }
                __syncthreads();
                // ---- H: softmax over s entries (wave 0) ----
                if (wv == 0) {
                    float v = (lane < s) ? sc[lane] : -3.0e38f;
                    float m = wmax(v);
                    float e = (lane < s) ? __expf(v - m) : 0.f;
                    float S = wred(e);
                    if (lane < 32) pw[lane] = e / S;
                }
                __syncthreads();
                // ---- I: ctx2 = sum_t' pw[t']*ref[t'], split even/odd t' ----
                if (d2 < 400) {
                    float a0 = 0.f, a1 = 0.f;
                    const unsigned* rr = (const unsigned*)REFh + (((size_t)l * BB + b) * TT) * 400 + d2;
#pragma unroll 4
                    for (int tp = gg; tp < s; tp += 2) {
                        h2 rv = u2h(rr[(size_t)tp * 400]);
                        float w = pw[tp];
                        a0 = fmaf(w, (float)rv[0], a0);
                        a1 = fmaf(w, (float)rv[1], a1);
                    }
                    if (gg == 1) pc[d2] = make_float2(a0, a1);
                    else { cin[2 * d2] = a0; cin[2 * d2 + 1] = a1; }  // stash (cell done with cin)
                }
                __syncthreads();
                if (tid < 400) xh[tid] = pack2(cin[2 * tid] + pc[tid].x, cin[2 * tid + 1] + pc[tid].y);
                __syncthreads();
                // ---- J: GEMV2: cat(ctx2, hv) @ sw + sb -> tanh -> layer out ----
                if (tid < DD) {
                    float acc = sb[l][tid];
                    const uint4* wp = swp[l] + tid;
#pragma unroll 8
                    for (int kq = 0; kq < 200; ++kq)
                        acc = dot8(wp[(size_t)kq * 800], xh4[kq], acc);
                    float lv = tanhf(acc);
                    REFh[(((size_t)l * BB + b) * TT + s) * DD + tid] = (__half)lv;
                    if (l == 0) cin[tid] = lv;          // next layer's input
                }
                __syncthreads();
            }
        }
    }

    // =================== head MLP for this block's 32 rows ===================
    unsigned* r8 = reinterpret_cast<unsigned*>(&HC[0][0][0]);   // 8 x 400 u32
    float* v1s = &cwS[0][0];                                     // 1600 f32
    float* v2s = &cwS[0][0] + 1600;                              // 400 f32
    const unsigned* refu = (const unsigned*)REFh + (((size_t)BB + b) * TT) * 400;  // l=1 rows
    for (int g = 0; g < 4; ++g) {
        for (int i = tid; i < 8 * 400; i += TPB)
            r8[i] = refu[(size_t)(g * 8 + i / 400) * 400 + (i % 400)];
        __syncthreads();
        for (int o = tid; o < 1600; o += TPB) {         // [8 rows][200 cols]
            int tr = o / 200, c = o % 200;
            float acc = hb1[c];
            const unsigned* rrow = &r8[tr * 400];
#pragma unroll 8
            for (int kp = 0; kp < 400; ++kp)
                acc = FDOT2(u2h(w1p[kp * 200 + c]), u2h(rrow[kp]), acc);
            v1s[o] = fmaxf(acc, 0.f);
        }
        __syncthreads();
        for (int o = tid; o < 400; o += TPB) {          // [8][50]
            int tr = o / 50, c = o % 50;
            float acc = hb2[c];
#pragma unroll 4
            for (int k = 0; k < 200; ++k) acc = fmaf(v1s[tr * 200 + k], hw2[k * 50 + c], acc);
            v2s[o] = fmaxf(acc, 0.f);
        }
        __syncthreads();
        for (int o = tid; o < 24; o += TPB) {           // [8][3]
            int tr = o / 3, oo = o % 3;
            float acc = hb3[oo];
            for (int k = 0; k < 50; ++k) acc = fmaf(v2s[tr * 50 + k], hw3[k * 3 + oo], acc);
            out[((size_t)b * TT + g * 8 + tr) * 3 + oo] = acc;
        }
        __syncthreads();
    }
}

extern "C" void kernel_launch(void* const* d_in, const int* in_sizes, int n_in,
                              void* d_out, int out_size, void* d_ws, size_t ws_size,
                              hipStream_t stream)
{
    const float* x_flat = (const float*)d_in[0];
    const float* enc    = (const float*)d_in[1];
    const float* init_h = (const float*)d_in[2];
    const float* init_c = (const float*)d_in[3];
    const float* cw0 = (const float*)d_in[4];
    const float* cb0 = (const float*)d_in[5];
    const float* cw1 = (const float*)d_in[6];
    const float* cb1 = (const float*)d_in[7];
    const float* iw0 = (const float*)d_in[8];
    const float* ib0 = (const float*)d_in[9];
    const float* iw1 = (const float*)d_in[10];
    const float* ib1 = (const float*)d_in[11];
    const float* sw0 = (const float*)d_in[12];
    const float* sb0 = (const float*)d_in[13];
    const float* sw1 = (const float*)d_in[14];
    const float* sb1 = (const float*)d_in[15];
    const float* hw1 = (const float*)d_in[16];
    const float* hb1 = (const float*)d_in[17];
    const float* hw2 = (const float*)d_in[18];
    const float* hb2 = (const float*)d_in[19];
    const float* hw3 = (const float*)d_in[20];
    const float* hb3 = (const float*)d_in[21];
    float* out = (float*)d_out;

    char* p = (char*)d_ws;
    uint4* iwp0 = (uint4*)p; p += (size_t)200 * 800 * 16;   // 2.56 MB each
    uint4* iwp1 = (uint4*)p; p += (size_t)200 * 800 * 16;
    uint4* swp0 = (uint4*)p; p += (size_t)200 * 800 * 16;
    uint4* swp1 = (uint4*)p; p += (size_t)200 * 800 * 16;
    __half* ench = (__half*)p; p += (size_t)BB * ENCL * DD * 2;        // 13.1 MB
    unsigned* w1p = (unsigned*)p; p += (size_t)400 * 200 * 4;          // 320 KB
    __half* PREh = (__half*)p; p += (size_t)2 * BB * TT * DD * 2;      // 6.55 MB
    __half* REFh = (__half*)p; p += (size_t)2 * BB * TT * DD * 2;      // 6.55 MB

    pack_w8<<<625, 256, 0, stream>>>(iw0, iwp0);
    pack_w8<<<625, 256, 0, stream>>>(iw1, iwp1);
    pack_w8<<<625, 256, 0, stream>>>(sw0, swp0);
    pack_w8<<<625, 256, 0, stream>>>(sw1, swp1);
    pack_pairs<<<12800, 256, 0, stream>>>(enc, (unsigned*)ench, BB * ENCL * DD / 2);
    pack_w1<<<313, 256, 0, stream>>>(hw1, w1p);

    decoder_kernel<<<BB, TPB, 0, stream>>>(
        x_flat, ench, iwp0, iwp1, swp0, swp1, ib0, ib1, sb0, sb1,
        cw0, cb0, cw1, cb1, init_h, init_c, PREh, REFh,
        w1p, hb1, hw2, hb2, hw3, hb3, out);
}

// Round 8
// 4367.604 us; speedup vs baseline: 2.0038x; 2.0038x over previous
//
#include <hip/hip_runtime.h>
#include <hip/hip_fp16.h>
#include <math.h>

#define BB 64
#define TT 32
#define ENCL 128
#define DD 800
#define TPB 1024
#define NBLK 256

typedef _Float16 h2 __attribute__((ext_vector_type(2)));

__device__ __forceinline__ h2 u2h(unsigned u) { union { unsigned u; h2 h; } c; c.u = u; return c.h; }
__device__ __forceinline__ unsigned pack2(float a, float b) {
    union { unsigned u; h2 h; } c; c.h[0] = (_Float16)a; c.h[1] = (_Float16)b; return c.u;
}
__device__ __forceinline__ float sigf(float x) { return 1.f / (1.f + __expf(-x)); }
__device__ __forceinline__ float wred(float v) {
#pragma unroll
    for (int o = 32; o > 0; o >>= 1) v += __shfl_xor(v, o);
    return v;
}
__device__ __forceinline__ float wmax(float v) {
#pragma unroll
    for (int o = 32; o > 0; o >>= 1) v = fmaxf(v, __shfl_xor(v, o));
    return v;
}

#if __has_builtin(__builtin_amdgcn_fdot2)
__device__ __forceinline__ float FDOT2(h2 a, h2 b, float c) { return __builtin_amdgcn_fdot2(a, b, c, false); }
#else
__device__ __forceinline__ float FDOT2(h2 a, h2 b, float c) {
    return c + (float)a[0] * (float)b[0] + (float)a[1] * (float)b[1];
}
#endif

__device__ __forceinline__ float dot8(uint4 w, uint4 x, float acc) {
    acc = FDOT2(u2h(w.x), u2h(x.x), acc);
    acc = FDOT2(u2h(w.y), u2h(x.y), acc);
    acc = FDOT2(u2h(w.z), u2h(x.z), acc);
    acc = FDOT2(u2h(w.w), u2h(x.w), acc);
    return acc;
}

// ---- 4-member group sync: RMW arrival on one per-row counter line (round-2-proven
// to reach the coherence point), relaxed poll + acquire fence, bounded watchdog ----
__device__ __forceinline__ void gsync(unsigned* cnt, int b, unsigned target) {
    __syncthreads();   // drain this block's stores (compiler emits vmcnt(0))
    if (threadIdx.x == 0) {
        __builtin_amdgcn_fence(__ATOMIC_RELEASE, "agent");
        __hip_atomic_fetch_add(&cnt[b * 32], 1u, __ATOMIC_RELAXED, __HIP_MEMORY_SCOPE_AGENT);
        int guard = 0;
        while (__hip_atomic_load(&cnt[b * 32], __ATOMIC_RELAXED, __HIP_MEMORY_SCOPE_AGENT) < target) {
            __builtin_amdgcn_s_sleep(1);
            if (++guard > (1 << 20)) break;   // watchdog: wrong answer beats a hang
        }
        __builtin_amdgcn_fence(__ATOMIC_ACQUIRE, "agent");
    }
    __syncthreads();
}

// ---- prep: GEMV1 column-sliced weights: [m][kq 0..199][cs 0..199] uint4 ----
__global__ __launch_bounds__(256) void pack_w1s(const float* __restrict__ W, uint4* __restrict__ out) {
    int i = blockIdx.x * 256 + threadIdx.x;
    if (i >= 160000) return;
    int cs = i % 200;
    int kq = (i / 200) % 200;
    int m  = i / 40000;
    const float* src = W + (size_t)(8 * kq) * 800 + 200 * m + cs;
    uint4 r;
    r.x = pack2(src[0],        src[800]);
    r.y = pack2(src[2 * 800],  src[3 * 800]);
    r.z = pack2(src[4 * 800],  src[5 * 800]);
    r.w = pack2(src[6 * 800],  src[7 * 800]);
    out[i] = r;
}

// ---- prep: GEMV2 k-sliced weights: [m][kq 0..49][c 0..799] uint4 ----
// kq<25: k = 200m + 8kq (ctx2 rows); kq>=25: k = 800 + 200m + 8(kq-25) (hv rows)
__global__ __launch_bounds__(256) void pack_w2s(const float* __restrict__ W, uint4* __restrict__ out) {
    int i = blockIdx.x * 256 + threadIdx.x;
    if (i >= 160000) return;
    int c  = i % 800;
    int kq = (i / 800) % 50;
    int m  = i / 40000;
    int kbase = (kq < 25) ? (200 * m + 8 * kq) : (800 + 200 * m + 8 * (kq - 25));
    const float* src = W + (size_t)kbase * 800 + c;
    uint4 r;
    r.x = pack2(src[0],        src[800]);
    r.y = pack2(src[2 * 800],  src[3 * 800]);
    r.z = pack2(src[4 * 800],  src[5 * 800]);
    r.w = pack2(src[6 * 800],  src[7 * 800]);
    out[i] = r;
}

__global__ __launch_bounds__(256) void pack_pairs(const float* __restrict__ in, unsigned* __restrict__ out, int n2) {
    int i = blockIdx.x * 256 + threadIdx.x;
    if (i < n2) out[i] = pack2(in[2 * i], in[2 * i + 1]);
}

__global__ __launch_bounds__(256) void pack_w1(const float* __restrict__ w1, unsigned* __restrict__ out) {
    int i = blockIdx.x * 256 + threadIdx.x;
    if (i >= 400 * 200) return;
    int c = i % 200, kp = i / 200;
    out[i] = pack2(w1[(2 * kp) * 200 + c], w1[(2 * kp + 1) * 200 + c]);
}

// =================== decoder: 4 blocks per batch row (b = bid&63, m = bid>>6) ===================
__global__ __launch_bounds__(TPB, 1) void decoder_kernel(
    const float* __restrict__ x, const __half* __restrict__ ench,
    const uint4* __restrict__ iw1s0, const uint4* __restrict__ iw1s1,
    const uint4* __restrict__ sw2s0, const uint4* __restrict__ sw2s1,
    const float* __restrict__ ib0, const float* __restrict__ ib1,
    const float* __restrict__ sb0, const float* __restrict__ sb1,
    const float* __restrict__ cw0, const float* __restrict__ cb0,
    const float* __restrict__ cw1, const float* __restrict__ cb1,
    const float* __restrict__ init_h, const float* __restrict__ init_c,
    __half* __restrict__ PREh, __half* __restrict__ REFh,
    float* __restrict__ PP, float* __restrict__ psc, unsigned* __restrict__ cnt,
    const unsigned* __restrict__ w1p, const float* __restrict__ hb1,
    const float* __restrict__ hw2, const float* __restrict__ hb2,
    const float* __restrict__ hw3, const float* __restrict__ hb3,
    float* __restrict__ out)
{
    __shared__ float cwS[2][1536];
    __shared__ float cbS[2][32];
    __shared__ float HC[2][2][DD];
    __shared__ float cin[DD];
    __shared__ float hn[DD];
    __shared__ float ctxf[DD];
    __shared__ float hv_s[200];
    __shared__ alignas(16) unsigned xh[DD];     // [0..399] ctx pairs, [400..799] hn / query pairs
    __shared__ alignas(16) unsigned xg2[200];   // GEMV2 input: 50 uint4
    __shared__ float sc[128];
    __shared__ float pw[128];
    __shared__ float pc1[4][200];               // GEMV1 k-split partials / float2 scratch

    const int bid = blockIdx.x;
    const int b = bid & 63;
    const int m = bid >> 6;
    const int tid = threadIdx.x;
    const int lane = tid & 63;
    const int wv = tid >> 6;
    const int d2 = tid & 511;
    const int gg = tid >> 9;
    const int c200 = (tid < 800) ? (tid % 200) : 0;
    const int q200 = (tid < 800) ? (tid / 200) : 0;

    const uint4* iwS[2] = {iw1s0, iw1s1};
    const uint4* swS[2] = {sw2s0, sw2s1};
    const float* ib[2] = {ib0, ib1};
    const float* sb[2] = {sb0, sb1};
    const float* cwA[2] = {cw0, cw1};
    const float* cbA[2] = {cb0, cb1};

    for (int l2 = 0; l2 < 2; ++l2) {
        const int cin_l = l2 ? 16 : 9;
        const int nw = 32 * cin_l * 3;
        for (int i = tid; i < nw; i += TPB) {
            int p = i % 3, rest = i / 3;
            int gt = rest & 3, rest2 = rest >> 2;
            int ic = rest2 % cin_l, ch = rest2 / cin_l;
            cwS[l2][(ch * cin_l + ic) * 12 + gt * 3 + p] = cwA[l2][((gt * 8 + ch) * cin_l + ic) * 3 + p];
        }
        for (int i = tid; i < 32; i += TPB) cbS[l2][i] = cbA[l2][i];
        for (int i = tid; i < DD; i += TPB) {
            HC[l2][0][i] = init_h[((size_t)l2 * BB + b) * DD + i];
            HC[l2][1][i] = init_c[((size_t)l2 * BB + b) * DD + i];
        }
    }
    __syncthreads();

    const unsigned* encb = (const unsigned*)ench + (size_t)b * ENCL * 400;
    const uint4* xh4 = (const uint4*)xh;
    float2* pcc = reinterpret_cast<float2*>(&pc1[0][0]);
    unsigned ep = 0;

    for (int s = 0; s < TT; ++s) {
        for (int l = 0; l < 2; ++l) {
            const int cinx = (l == 0) ? 1 : 8;
            const int cin_l = cinx + 8;
            // PP double-buffer by stage parity: kills read(stage k) vs write(stage k+1) races
            float* PPc = PP + (size_t)((s * 2 + l) & 1) * (NBLK * 800);
            // ---- A: cell input ----
            if (l == 0) {
                if (tid < 100) cin[tid] = x[((size_t)b * TT + s) * 100 + tid];
            }
            __syncthreads();
            // ---- B: ConvLSTM cell (redundant across members) ----
            if (tid < DD) {
                const int col = tid % 10, rch = tid / 10;
                const int ch = rch & 7, r = rch >> 3;
                float g0 = cbS[l][ch], g1 = cbS[l][8 + ch], g2 = cbS[l][16 + ch], g3 = cbS[l][24 + ch];
                for (int ic = 0; ic < cin_l; ++ic) {
                    const float* zb = (ic < cinx)
                        ? ((l == 0) ? &cin[r * 10] : &cin[r * 80 + ic * 10])
                        : &HC[l][0][r * 80 + (ic - cinx) * 10];
                    float z0 = (col > 0) ? zb[col - 1] : 0.f;
                    float z1 = zb[col];
                    float z2 = (col < 9) ? zb[col + 1] : 0.f;
                    const float* wr = &cwS[l][(ch * cin_l + ic) * 12];
                    g0 += z0 * wr[0] + z1 * wr[1] + z2 * wr[2];
                    g1 += z0 * wr[3] + z1 * wr[4] + z2 * wr[5];
                    g2 += z0 * wr[6] + z1 * wr[7] + z2 * wr[8];
                    g3 += z0 * wr[9] + z1 * wr[10] + z2 * wr[11];
                }
                float c2 = sigf(g1) * HC[l][1][tid] + sigf(g0) * tanhf(g2);
                float hnv = sigf(g3) * tanhf(c2);
                hn[tid] = hnv;
                HC[l][1][tid] = c2;
            }
            __syncthreads();
            if (tid < DD) HC[l][0][tid] = hn[tid];
            if (tid < 400) xh[400 + tid] = pack2(hn[2 * tid], hn[2 * tid + 1]);
            __syncthreads();
            // ---- C: inter-attn scores, redundant: 16 waves x 8 rows ----
            {
                const uint4* xq0 = (const uint4*)(xh + 400);
#pragma unroll
                for (int r8 = 0; r8 < 8; ++r8) {
                    const int le = wv * 8 + r8;
                    const uint4* erow4 = (const uint4*)(encb + (size_t)le * 400);
                    float sum = dot8(erow4[lane], xq0[lane], 0.f);
                    if (lane < 36) sum = dot8(erow4[64 + lane], xq0[64 + lane], sum);
                    sum = wred(sum);
                    if (lane == 0) sc[le] = sum;
                }
            }
            __syncthreads();
            // ---- D: softmax over 128 ----
            if (wv == 0) {
                float v0 = sc[lane], v1 = sc[64 + lane];
                float mm = wmax(fmaxf(v0, v1));
                float e0 = __expf(v0 - mm), e1 = __expf(v1 - mm);
                float S = wred(e0 + e1);
                float inv = 1.f / S;
                pw[lane] = e0 * inv;
                pw[64 + lane] = e1 * inv;
            }
            __syncthreads();
            // ---- E: ctx redundant, split le halves across 2 thread groups ----
            if (d2 < 400) {
                float a0 = 0.f, a1 = 0.f;
                const unsigned* ep2 = encb + (size_t)(gg * 64) * 400 + d2;
#pragma unroll 8
                for (int k = 0; k < 64; ++k) {
                    h2 ev = u2h(ep2[(size_t)k * 400]);
                    float w = pw[gg * 64 + k];
                    a0 = fmaf(w, (float)ev[0], a0);
                    a1 = fmaf(w, (float)ev[1], a1);
                }
                if (gg == 1) pcc[d2] = make_float2(a0, a1);
                else { ctxf[2 * d2] = a0; ctxf[2 * d2 + 1] = a1; }
            }
            __syncthreads();
            if (tid < 400) xh[tid] = pack2(ctxf[2 * tid] + pcc[tid].x, ctxf[2 * tid + 1] + pcc[tid].y);
            __syncthreads();
            // ---- F: GEMV1 column slice [200m,200m+200), k split 4-way ----
            if (tid < 800) {
                float acc = 0.f;
                const uint4* wp = iwS[l] + (size_t)m * 40000 + (size_t)(50 * q200) * 200 + c200;
                const uint4* xv = xh4 + 50 * q200;
#pragma unroll 10
                for (int i = 0; i < 50; ++i)
                    acc = dot8(wp[(size_t)i * 200], xv[i], acc);
                pc1[q200][c200] = acc;
            }
            __syncthreads();
            if (tid < 200) {
                float v = tanhf(pc1[0][tid] + pc1[1][tid] + pc1[2][tid] + pc1[3][tid] + ib[l][200 * m + tid]);
                hv_s[tid] = v;
                PREh[((size_t)(l * BB + b) * TT + s) * DD + 200 * m + tid] = (__half)v;
            }
            __syncthreads();
            if (tid < 100) xh[400 + tid] = pack2(hv_s[2 * tid], hv_s[2 * tid + 1]);  // query slice
            __syncthreads();

            if (s == 0) {
                // exchange hv slices -> full layer output
                if (tid < 200) PPc[((size_t)(b * 4 + m)) * 800 + 200 * m + tid] = hv_s[tid];
                gsync(cnt, b, 4 * (++ep));
                if (tid < 800) {
                    int mo = tid / 200;
                    float v = PPc[((size_t)(b * 4 + mo)) * 800 + tid];
                    cin[tid] = v;
                    if (mo == m) REFh[((size_t)(l * BB + b) * TT + 0) * DD + tid] = (__half)v;
                }
                __syncthreads();
            } else {
                // ---- G: partial self-attn scores over slice m ----
                {
                    const uint4* xq4 = (const uint4*)(xh + 400);
                    for (int tp = wv; tp < s; tp += 16) {
                        const uint4* pr4 = (const uint4*)((const unsigned*)PREh
                            + ((size_t)(l * BB + b) * TT + tp) * 400 + 100 * m);
                        float sum = (lane < 25) ? dot8(pr4[lane], xq4[lane], 0.f) : 0.f;
                        sum = wred(sum);
                        if (lane == 0) psc[((size_t)(b * 4 + m)) * 32 + tp] = sum;
                    }
                }
                gsync(cnt, b, 4 * (++ep));
                // ---- H: softmax over s (sum 4 partials, redundant) ----
                if (wv == 0) {
                    float v = -3.0e38f;
                    if (lane < s) {
                        v = psc[((size_t)(b * 4 + 0)) * 32 + lane] + psc[((size_t)(b * 4 + 1)) * 32 + lane]
                          + psc[((size_t)(b * 4 + 2)) * 32 + lane] + psc[((size_t)(b * 4 + 3)) * 32 + lane];
                    }
                    float mm = wmax(v);
                    float e = (lane < s) ? __expf(v - mm) : 0.f;
                    float S = wred(e);
                    if (lane < 32) pw[lane] = e / S;
                }
                __syncthreads();
                // ---- I: ctx2 redundant, split t' parity across 2 groups ----
                if (d2 < 400) {
                    float a0 = 0.f, a1 = 0.f;
                    const unsigned* rr = (const unsigned*)REFh + ((size_t)(l * BB + b) * TT) * 400 + d2;
#pragma unroll 4
                    for (int tp = gg; tp < s; tp += 2) {
                        h2 rv = u2h(rr[(size_t)tp * 400]);
                        float w = pw[tp];
                        a0 = fmaf(w, (float)rv[0], a0);
                        a1 = fmaf(w, (float)rv[1], a1);
                    }
                    if (gg == 1) pcc[d2] = make_float2(a0, a1);
                    else { ctxf[2 * d2] = a0; ctxf[2 * d2 + 1] = a1; }
                }
                __syncthreads();
                if (tid < 400) {
                    ctxf[2 * tid] += pcc[tid].x;
                    ctxf[2 * tid + 1] += pcc[tid].y;
                }
                __syncthreads();
                // pack GEMV2 input: [0..99] ctx2 slice m, [100..199] hv slice m
                if (tid < 100) xg2[tid] = pack2(ctxf[200 * m + 2 * tid], ctxf[200 * m + 2 * tid + 1]);
                else if (tid < 200) { int i = tid - 100; xg2[tid] = pack2(hv_s[2 * i], hv_s[2 * i + 1]); }
                __syncthreads();
                // ---- J: GEMV2 k-slice -> partial over all 800 outputs ----
                if (tid < 800) {
                    float acc = 0.f;
                    const uint4* wp = swS[l] + (size_t)m * 40000 + tid;
                    const uint4* xv = (const uint4*)xg2;
#pragma unroll 10
                    for (int kq = 0; kq < 50; ++kq)
                        acc = dot8(wp[(size_t)kq * 800], xv[kq], acc);
                    PPc[((size_t)(b * 4 + m)) * 800 + tid] = acc;
                }
                gsync(cnt, b, 4 * (++ep));
                if (tid < 800) {
                    float o = PPc[((size_t)(b * 4 + 0)) * 800 + tid] + PPc[((size_t)(b * 4 + 1)) * 800 + tid]
                            + PPc[((size_t)(b * 4 + 2)) * 800 + tid] + PPc[((size_t)(b * 4 + 3)) * 800 + tid]
                            + sb[l][tid];
                    float v = tanhf(o);
                    cin[tid] = v;
                    if ((unsigned)(tid - 200 * m) < 200u)
                        REFh[((size_t)(l * BB + b) * TT + s) * DD + tid] = (__half)v;
                }
                __syncthreads();
            }
        }
    }

    gsync(cnt, b, 4 * (++ep));   // REFh row 31 slices visible for head

    // =================== head MLP: member m handles t in [8m, 8m+8) ===================
    unsigned* r8 = reinterpret_cast<unsigned*>(&HC[0][0][0]);   // 8 x 400 u32
    float* v1s = &cwS[0][0];                                     // 1600 f32
    float* v2s = &cwS[0][0] + 1600;                              // 400 f32
    const unsigned* refu = (const unsigned*)REFh + (((size_t)BB + b) * TT) * 400;
    {
        for (int i = tid; i < 8 * 400; i += TPB)
            r8[i] = refu[(size_t)(m * 8 + i / 400) * 400 + (i % 400)];
        __syncthreads();
        for (int o = tid; o < 1600; o += TPB) {
            int tr = o / 200, c = o % 200;
            float acc = hb1[c];
            const unsigned* rrow = &r8[tr * 400];
#pragma unroll 8
            for (int kp = 0; kp < 400; ++kp)
                acc = FDOT2(u2h(w1p[kp * 200 + c]), u2h(rrow[kp]), acc);
            v1s[o] = fmaxf(acc, 0.f);
        }
        __syncthreads();
        for (int o = tid; o < 400; o += TPB) {
            int tr = o / 50, c = o % 50;
            float acc = hb2[c];
#pragma unroll 4
            for (int k = 0; k < 200; ++k) acc = fmaf(v1s[tr * 200 + k], hw2[k * 50 + c], acc);
            v2s[o] = fmaxf(acc, 0.f);
        }
        __syncthreads();
        for (int o = tid; o < 24; o += TPB) {
            int tr = o / 3, oo = o % 3;
            float acc = hb3[oo];
            for (int k = 0; k < 50; ++k) acc = fmaf(v2s[tr * 50 + k], hw3[k * 3 + oo], acc);
            out[((size_t)b * TT + m * 8 + tr) * 3 + oo] = acc;
        }
    }
}

extern "C" void kernel_launch(void* const* d_in, const int* in_sizes, int n_in,
                              void* d_out, int out_size, void* d_ws, size_t ws_size,
                              hipStream_t stream)
{
    const float* x_flat = (const float*)d_in[0];
    const float* enc    = (const float*)d_in[1];
    const float* init_h = (const float*)d_in[2];
    const float* init_c = (const float*)d_in[3];
    const float* cw0 = (const float*)d_in[4];
    const float* cb0 = (const float*)d_in[5];
    const float* cw1 = (const float*)d_in[6];
    const float* cb1 = (const float*)d_in[7];
    const float* iw0 = (const float*)d_in[8];
    const float* ib0 = (const float*)d_in[9];
    const float* iw1 = (const float*)d_in[10];
    const float* ib1 = (const float*)d_in[11];
    const float* sw0 = (const float*)d_in[12];
    const float* sb0 = (const float*)d_in[13];
    const float* sw1 = (const float*)d_in[14];
    const float* sb1 = (const float*)d_in[15];
    const float* hw1 = (const float*)d_in[16];
    const float* hb1 = (const float*)d_in[17];
    const float* hw2 = (const float*)d_in[18];
    const float* hb2 = (const float*)d_in[19];
    const float* hw3 = (const float*)d_in[20];
    const float* hb3 = (const float*)d_in[21];
    float* out = (float*)d_out;

    char* p = (char*)d_ws;
    uint4* iw1s0 = (uint4*)p; p += (size_t)160000 * 16;   // 2.56 MB
    uint4* iw1s1 = (uint4*)p; p += (size_t)160000 * 16;
    uint4* sw2s0 = (uint4*)p; p += (size_t)160000 * 16;
    uint4* sw2s1 = (uint4*)p; p += (size_t)160000 * 16;
    __half* ench = (__half*)p; p += (size_t)BB * ENCL * DD * 2;        // 13.1 MB
    unsigned* w1p = (unsigned*)p; p += (size_t)400 * 200 * 4;          // 320 KB
    __half* PREh = (__half*)p; p += (size_t)2 * BB * TT * DD * 2;      // 6.55 MB
    __half* REFh = (__half*)p; p += (size_t)2 * BB * TT * DD * 2;      // 6.55 MB
    float* PP    = (float*)p; p += (size_t)2 * NBLK * 800 * 4;         // 1.64 MB (double-buffered)
    float* psc   = (float*)p; p += (size_t)NBLK * 32 * 4;              // 32 KB
    unsigned* cnt = (unsigned*)p; p += (size_t)BB * 32 * 4;            // 8 KB (one line per row)

    (void)hipMemsetAsync(cnt, 0, (size_t)BB * 32 * 4, stream);

    pack_w1s<<<625, 256, 0, stream>>>(iw0, iw1s0);
    pack_w1s<<<625, 256, 0, stream>>>(iw1, iw1s1);
    pack_w2s<<<625, 256, 0, stream>>>(sw0, sw2s0);
    pack_w2s<<<625, 256, 0, stream>>>(sw1, sw2s1);
    pack_pairs<<<12800, 256, 0, stream>>>(enc, (unsigned*)ench, BB * ENCL * DD / 2);
    pack_w1<<<313, 256, 0, stream>>>(hw1, w1p);

    decoder_kernel<<<NBLK, TPB, 0, stream>>>(
        x_flat, ench, iw1s0, iw1s1, sw2s0, sw2s1, ib0, ib1, sb0, sb1,
        cw0, cb0, cw1, cb1, init_h, init_c, PREh, REFh, PP, psc, cnt,
        w1p, hb1, hw2, hb2, hw3, hb3, out);
}